// Round 14
// baseline (250.047 us; speedup 1.0000x reference)
//
#include <hip/hip_runtime.h>
#include <hip/hip_bf16.h>
#include <hip/hip_cooperative_groups.h>

namespace cg = cooperative_groups;

// N=10000 nodes, F=256, H=256, E=320000 edges.
//
// W1 = [W1a | W1b]:  U' = x @ W1a^T + b1 (bias folded), V = x @ W1b^T
// out[e] = sigmoid(b2 + sum_j relu(U'[row][j] + V[col][j]) * W2[j])
// uv layout (fp8 e4m3, HW cvt): uv[node] = 512 bytes: [0:256]=U', [256:512]=V.
//
// R14: ONE cooperative dispatch. Evidence for ~10-15us per-dispatch overhead:
// R12 (+1 gemm dispatch = +28us, but gemm body models at ~5-10us), R9 (+1
// dispatch = +19us beyond kernel time), R13 (removing 7/8 barriers + 2x
// blocks = only -3us). R6's fused-kernel spill is fixed: acc[4] gemm (not
// acc[8]), single-batch edge (pairing was neutral, R7), and NO launch_bounds
// min-waves clamp (R6's (256,4) forced <=128 VGPR -> scratch spill).
//
// Journal: R8/R9 sort-for-locality -> sort cost >> ~20us gain. R11 fp8 uv:
// -14.7us (L2 line halving). Harness tax ~47us/window (268MB ws poison fill
// + restores) — not controllable.

typedef __attribute__((ext_vector_type(8))) short bf16x8;
typedef __attribute__((ext_vector_type(4))) float f32x4;
typedef __attribute__((ext_vector_type(2))) float f32x2;

__device__ __forceinline__ unsigned short f2bf(float f) {
    __hip_bfloat16 h = __float2bfloat16(f);
    return *reinterpret_cast<unsigned short*>(&h);
}

__device__ __forceinline__ unsigned char f2fp8(float f) {
    return (unsigned char)(__builtin_amdgcn_cvt_pk_fp8_f32(f, f, 0, false) & 0xff);
}

__global__ __launch_bounds__(256) void fused_kernel(
        const float* __restrict__ x, const int* __restrict__ ei,
        const float* __restrict__ W1, const float* __restrict__ b1,
        const float* __restrict__ w2, const float* __restrict__ b2p,
        float* __restrict__ out, unsigned char* __restrict__ uv,
        unsigned short* __restrict__ wb, int M, int E) {
    __shared__ __align__(16) unsigned short As[16][264];   // 8.25 KB

    cg::grid_group grid = cg::this_grid();
    const int t    = threadIdx.x;
    const int wave = t >> 6;
    const int lane = t & 63;
    const int lm   = lane & 15;
    const int lq   = lane >> 4;
    const int lk   = lq * 8;
    const int nblk = gridDim.x;

    // ---------------- Phase 0: W1 fp32 -> bf16 (512 KB) -------------------
    for (int i = blockIdx.x * 256 + t; i < 32768; i += nblk * 256) {
        float4 v = ((const float4*)W1)[i];
        ushort4 o = {f2bf(v.x), f2bf(v.y), f2bf(v.z), f2bf(v.w)};
        ((ushort4*)wb)[i] = o;
    }
    grid.sync();

    // ---------------- Phase 1: gemm, grid-stride over 1250 tiles ----------
    // tile = (mt, h): h = tile&1 selects U/V half; block = 16 rows x 256
    // cols of that half. Stage full 16x256 A-tile once (stride 264: 2-way
    // bank alias = free), ONE __syncthreads, barrier-free K-loop
    // (8 ktiles x 4 MFMA). C/D: col=lane&15, row=(lane>>4)*4+reg.
    const int ntile = ((M + 15) / 16) * 2;
    for (int tile = blockIdx.x; tile < ntile; tile += nblk) {
        const int h  = tile & 1;
        const int m0 = (tile >> 1) * 16;

        {   // stage A: thread t covers row (t>>4), cols (t&15)*4 + i*64
            const int srow = t >> 4;
            const int scol = (t & 15) * 4;
            const int gr   = m0 + srow;
            const float* xr = x + (size_t)(gr < M ? gr : (M - 1)) * 256;
#pragma unroll
            for (int i = 0; i < 4; ++i) {
                float4 v = *(const float4*)(xr + scol + i * 64);
                ushort4 o = {f2bf(v.x), f2bf(v.y), f2bf(v.z), f2bf(v.w)};
                *(ushort4*)&As[srow][scol + i * 64] = o;
            }
        }
        __syncthreads();

        const unsigned short* bpre =
            wb + (size_t)(wave * 64 + lm) * 512 + h * 256 + lk;

        f32x4 acc[4];
#pragma unroll
        for (int j = 0; j < 4; ++j) acc[j] = f32x4{0.f, 0.f, 0.f, 0.f};

#pragma unroll 4
        for (int kt = 0; kt < 256; kt += 32) {
            bf16x8 a = *(const bf16x8*)&As[lm][kt + lk];
#pragma unroll
            for (int j = 0; j < 4; ++j) {
                bf16x8 b = *(const bf16x8*)(bpre + (size_t)j * 16 * 512 + kt);
                acc[j] = __builtin_amdgcn_mfma_f32_16x16x32_bf16(a, b, acc[j], 0, 0, 0);
            }
        }

        const int row0 = m0 + lq * 4;
#pragma unroll
        for (int j = 0; j < 4; ++j) {
            const int cin  = wave * 64 + j * 16 + lm;
            const int col  = h * 256 + cin;
            const float badd = h ? 0.f : b1[cin];
#pragma unroll
            for (int r = 0; r < 4; ++r) {
                if (row0 + r < M)
                    uv[(size_t)(row0 + r) * 512 + col] = f2fp8(acc[j][r] + badd);
            }
        }
        __syncthreads();   // As reuse guard before next grid-stride tile
    }
    grid.sync();

    // ---------------- Phase 2: edge, grid-stride single-batch -------------
    // 4 edges/batch (g=lane>>4 slot, c=lane&15 col chunk); per lane one
    // uint4 (16 fp8) per U row + one per V row; HW fp8 decode.
    const int g = lq;
    const int c = lm;
    const int wid  = blockIdx.x * 4 + wave;
    const int nwav = nblk * 4;
    const int nb   = E >> 2;

    float w2r[16];
#pragma unroll
    for (int i = 0; i < 4; ++i)
        *(float4*)&w2r[i * 4] = *(const float4*)(w2 + c * 16 + i * 4);
    const float b2 = b2p[0];

    for (int b = wid; b < nb; b += nwav) {
        const int e   = b * 4 + g;
        const int row = ei[e];
        const int col = ei[E + e];

        uint4 ua = *(const uint4*)(uv + (size_t)row * 512 + c * 16);
        uint4 va = *(const uint4*)(uv + (size_t)col * 512 + 256 + c * 16);

        unsigned int uw[4], vw[4];
        *(uint4*)&uw[0] = ua; *(uint4*)&vw[0] = va;

        float2 p2 = {0.f, 0.f};
#pragma unroll
        for (int w = 0; w < 4; ++w) {
            f32x2 u01 = __builtin_amdgcn_cvt_pk_f32_fp8(uw[w], false);
            f32x2 u23 = __builtin_amdgcn_cvt_pk_f32_fp8(uw[w], true);
            f32x2 v01 = __builtin_amdgcn_cvt_pk_f32_fp8(vw[w], false);
            f32x2 v23 = __builtin_amdgcn_cvt_pk_f32_fp8(vw[w], true);
            float s0 = fmaxf(u01.x + v01.x, 0.f);
            float s1 = fmaxf(u01.y + v01.y, 0.f);
            float s2 = fmaxf(u23.x + v23.x, 0.f);
            float s3 = fmaxf(u23.y + v23.y, 0.f);
            p2.x = fmaf(s0, w2r[4 * w + 0], p2.x);
            p2.y = fmaf(s1, w2r[4 * w + 1], p2.y);
            p2.x = fmaf(s2, w2r[4 * w + 2], p2.x);
            p2.y = fmaf(s3, w2r[4 * w + 3], p2.y);
        }
        float p = p2.x + p2.y;

#pragma unroll
        for (int off = 1; off < 16; off <<= 1)
            p += __shfl_xor(p, off, 64);

        if (c == 0) out[e] = 1.f / (1.f + __expf(-(p + b2)));
    }
}

extern "C" void kernel_launch(void* const* d_in, const int* in_sizes, int n_in,
                              void* d_out, int out_size, void* d_ws, size_t ws_size,
                              hipStream_t stream) {
    const float* x  = (const float*)d_in[0];
    const int*   ei = (const int*)d_in[1];
    const float* W1 = (const float*)d_in[2];
    const float* b1 = (const float*)d_in[3];
    const float* W2 = (const float*)d_in[4];
    const float* b2 = (const float*)d_in[5];
    float* out = (float*)d_out;

    int N = in_sizes[0] / 256;   // 10000
    int E = in_sizes[1] / 2;     // 320000

    unsigned char*  uv = (unsigned char*)d_ws;                    // N*512 fp8
    unsigned short* wb = (unsigned short*)(uv + (size_t)N * 512); // 256KB bf16

    // Cooperative grid sized for guaranteed co-residency (host-side query,
    // deterministic, capture-safe).
    int maxBlk = 0;
    hipOccupancyMaxActiveBlocksPerMultiprocessor(&maxBlk,
                                                 (const void*)fused_kernel,
                                                 256, 0);
    if (maxBlk < 1) maxBlk = 1;
    if (maxBlk > 8) maxBlk = 8;
    int grid = maxBlk * 256;

    void* args[] = {(void*)&x, (void*)&ei, (void*)&W1, (void*)&b1, (void*)&W2,
                    (void*)&b2, (void*)&out, (void*)&uv, (void*)&wb,
                    (void*)&N, (void*)&E};
    hipLaunchCooperativeKernel((void*)fused_kernel, dim3(grid), dim3(256),
                               args, 0, stream);
}

// Round 15
// 111.313 us; speedup vs baseline: 2.2463x; 2.2463x over previous
//
#include <hip/hip_runtime.h>
#include <hip/hip_bf16.h>

// N=10000 nodes, F=256, H=256, E=320000 edges.
//
// W1 = [W1a | W1b]:  U' = x @ W1a^T + b1 (bias folded), V = x @ W1b^T
// out[e] = sigmoid(b2 + sum_j relu(U'[row][j] + V[col][j]) * W2[j])
// uv layout (fp8 e4m3, HW cvt): uv[node] = 512 bytes: [0:256]=U', [256:512]=V.
//
// R15 = R13 structure + OPERAND-SWAPPED MFMA in the gemm:
//   acc = mfma(W1frag, xfrag, acc)  ->  D[m=W1row][n=node]
//   C/D: n=lane&15 -> node (one node/lane), m=(lane>>4)*4+reg -> 4
//   CONSECUTIVE uv cols -> pack 4 fp8 into a dword (2x cvt_pk_fp8) ->
//   4 dword stores/lane vs R13's 16 scattered byte stores (5.12M -> 1.28M
//   store instrs). A/B load addresses unchanged (fragment layouts are
//   symmetric); arithmetic bit-identical.
//
// Journal: R6+R14 fused coop kernel -> 288/250us (spill / latency-parked;
// fusion structurally wrong here). R8/R9 sort-for-locality -> 75-96us sort
// >> ~20us gain. R7 deeper edge ILP -> neutral (edge L2 line-bound ~25us).
// R11 fp8 uv: -14.7us. R12 measured gemm+1gap = 28us. R13 single-barrier
// K-loop + 2x blocks: -3us. Harness tax ~47us fill + restores per window.

typedef __attribute__((ext_vector_type(8))) short bf16x8;
typedef __attribute__((ext_vector_type(4))) float f32x4;
typedef __attribute__((ext_vector_type(2))) float f32x2;

__device__ __forceinline__ unsigned short f2bf(float f) {
    __hip_bfloat16 h = __float2bfloat16(f);
    return *reinterpret_cast<unsigned short*>(&h);
}

// ---------------------------------------------------------------------------
// Kernel 0: convert W1 (256x512 fp32) to bf16. Tiny (~2us).
// ---------------------------------------------------------------------------
__global__ __launch_bounds__(256) void convert_w(const float* __restrict__ w1,
                                                 unsigned short* __restrict__ wb,
                                                 int nw4) {
    int i = blockIdx.x * 256 + threadIdx.x;
    if (i < nw4) {
        float4 v = ((const float4*)w1)[i];
        ushort4 o = {f2bf(v.x), f2bf(v.y), f2bf(v.z), f2bf(v.w)};
        ((ushort4*)wb)[i] = o;
    }
}

// ---------------------------------------------------------------------------
// Kernel 1 v7: grid (625, 2). Block = 16 nodes x 256 cols of half h.
// Stage full 16x256 A-tile (x, fp32->bf16) to LDS once (stride 264: 2-way
// bank alias = free), ONE barrier, barrier-free K-loop.
// MFMA operands SWAPPED: A = W1-frag (m = W1 row = uv col), B = x-frag
// (n = node). Per wave, n-tile j covers uv cols wave*64+j*16..+15.
//   W1-frag: wb row (wave*64 + j*16 + lm), k = h*256 + kt + lq*8  (16B)
//   x-frag:  As[lm][kt + lq*8]                                    (16B)
//   D: node = m0 + lm; cols = wave*64 + j*16 + lq*4 + (0..3)
// Epilogue: bias (h=0 only) + 2x cvt_pk_fp8 -> one dword store per n-tile.
// ---------------------------------------------------------------------------
__global__ __launch_bounds__(256) void gemm_mfma(const float* __restrict__ x,
                                                 const unsigned short* __restrict__ wb,
                                                 const float* __restrict__ b1,
                                                 unsigned char* __restrict__ uv,
                                                 int M) {
    __shared__ __align__(16) unsigned short As[16][264];   // 8.25 KB

    const int t    = threadIdx.x;
    const int wave = t >> 6;
    const int lane = t & 63;
    const int lm   = lane & 15;
    const int lq   = lane >> 4;
    const int lk   = lq * 8;
    const int m0   = blockIdx.x * 16;
    const int h    = blockIdx.y;               // 0: U half, 1: V half

    // ---- stage A: thread t covers row (t>>4), cols (t&15)*4 + i*64 ----
    {
        const int srow = t >> 4;
        const int scol = (t & 15) * 4;
        const int gr   = m0 + srow;
        const float* xr = x + (size_t)(gr < M ? gr : (M - 1)) * 256;
#pragma unroll
        for (int i = 0; i < 4; ++i) {
            float4 v = *(const float4*)(xr + scol + i * 64);
            ushort4 o = {f2bf(v.x), f2bf(v.y), f2bf(v.z), f2bf(v.w)};
            *(ushort4*)&As[srow][scol + i * 64] = o;
        }
    }
    __syncthreads();

    // W1 pointer: row (wave*64 + j*16 + lm), k-half h
    const unsigned short* bpre =
        wb + (size_t)(wave * 64 + lm) * 512 + h * 256 + lk;

    f32x4 acc[4];
#pragma unroll
    for (int j = 0; j < 4; ++j) acc[j] = f32x4{0.f, 0.f, 0.f, 0.f};

#pragma unroll 4
    for (int kt = 0; kt < 256; kt += 32) {
        bf16x8 xf = *(const bf16x8*)&As[lm][kt + lk];
#pragma unroll
        for (int j = 0; j < 4; ++j) {
            bf16x8 w = *(const bf16x8*)(bpre + (size_t)j * 16 * 512 + kt);
            // swapped: A = W1 (m = uv col), B = x (n = node)
            acc[j] = __builtin_amdgcn_mfma_f32_16x16x32_bf16(w, xf, acc[j], 0, 0, 0);
        }
    }

    // ---- epilogue: node = m0+lm; 4 consecutive cols per n-tile -> dword ----
    const int node = m0 + lm;
    if (node < M) {
        unsigned char* up = uv + (size_t)node * 512 + h * 256 + wave * 64 + lq * 4;
#pragma unroll
        for (int j = 0; j < 4; ++j) {
            float4 bb = h ? float4{0.f, 0.f, 0.f, 0.f}
                          : *(const float4*)(b1 + wave * 64 + j * 16 + lq * 4);
            unsigned int d = __builtin_amdgcn_cvt_pk_fp8_f32(
                acc[j][0] + bb.x, acc[j][1] + bb.y, 0, false);
            d = __builtin_amdgcn_cvt_pk_fp8_f32(
                acc[j][2] + bb.z, acc[j][3] + bb.w, d, true);
            *(unsigned int*)(up + j * 16) = d;
        }
    }
}

// ---------------------------------------------------------------------------
// Kernel 2 (R11, unchanged): edge phase over fp8 uv. 4 edges/batch
// (g=lane>>4 slot, c=lane&15 col chunk); per lane one uint4 (16 fp8) per
// U row + one per V row; two independent batches per iteration; HW decode.
// ---------------------------------------------------------------------------
__global__ __launch_bounds__(256) void edge_kernel(const unsigned char* __restrict__ uv,
                                                   const int* __restrict__ ei,
                                                   const float* __restrict__ w2,
                                                   const float* __restrict__ b2p,
                                                   float* __restrict__ out, int E) {
    const int lane = threadIdx.x & 63;
    const int g = lane >> 4;
    const int c = lane & 15;
    const int wid  = (blockIdx.x * blockDim.x + threadIdx.x) >> 6;
    const int nwav = (gridDim.x * blockDim.x) >> 6;
    const int nb   = E >> 2;

    float w2r[16];
#pragma unroll
    for (int i = 0; i < 4; ++i)
        *(float4*)&w2r[i * 4] = *(const float4*)(w2 + c * 16 + i * 4);
    const float b2 = b2p[0];

    for (int b = wid; b < nb; b += 2 * nwav) {
        const int bB = b + nwav;
        const bool has2 = bB < nb;

        const int e0 = b * 4 + g;
        const int r0 = ei[e0];
        const int c0 = ei[E + e0];
        const int e1 = has2 ? bB * 4 + g : e0;
        const int r1 = ei[e1];
        const int c1 = ei[E + e1];

        uint4 ua = *(const uint4*)(uv + (size_t)r0 * 512 + c * 16);
        uint4 va = *(const uint4*)(uv + (size_t)c0 * 512 + 256 + c * 16);
        uint4 ub = *(const uint4*)(uv + (size_t)r1 * 512 + c * 16);
        uint4 vb = *(const uint4*)(uv + (size_t)c1 * 512 + 256 + c * 16);

        unsigned int uw[4], vw[4];
        float p;

        // ---- batch A ----
        *(uint4*)&uw[0] = ua; *(uint4*)&vw[0] = va;
        {
            float2 p2 = {0.f, 0.f};
#pragma unroll
            for (int w = 0; w < 4; ++w) {
                f32x2 u01 = __builtin_amdgcn_cvt_pk_f32_fp8(uw[w], false);
                f32x2 u23 = __builtin_amdgcn_cvt_pk_f32_fp8(uw[w], true);
                f32x2 v01 = __builtin_amdgcn_cvt_pk_f32_fp8(vw[w], false);
                f32x2 v23 = __builtin_amdgcn_cvt_pk_f32_fp8(vw[w], true);
                float s0 = fmaxf(u01.x + v01.x, 0.f);
                float s1 = fmaxf(u01.y + v01.y, 0.f);
                float s2 = fmaxf(u23.x + v23.x, 0.f);
                float s3 = fmaxf(u23.y + v23.y, 0.f);
                p2.x = fmaf(s0, w2r[4 * w + 0], p2.x);
                p2.y = fmaf(s1, w2r[4 * w + 1], p2.y);
                p2.x = fmaf(s2, w2r[4 * w + 2], p2.x);
                p2.y = fmaf(s3, w2r[4 * w + 3], p2.y);
            }
            p = p2.x + p2.y;
        }
#pragma unroll
        for (int off = 1; off < 16; off <<= 1)
            p += __shfl_xor(p, off, 64);
        if (c == 0) out[e0] = 1.f / (1.f + __expf(-(p + b2)));

        // ---- batch B ----
        if (has2) {
            *(uint4*)&uw[0] = ub; *(uint4*)&vw[0] = vb;
            float2 p2 = {0.f, 0.f};
#pragma unroll
            for (int w = 0; w < 4; ++w) {
                f32x2 u01 = __builtin_amdgcn_cvt_pk_f32_fp8(uw[w], false);
                f32x2 u23 = __builtin_amdgcn_cvt_pk_f32_fp8(uw[w], true);
                f32x2 v01 = __builtin_amdgcn_cvt_pk_f32_fp8(vw[w], false);
                f32x2 v23 = __builtin_amdgcn_cvt_pk_f32_fp8(vw[w], true);
                float s0 = fmaxf(u01.x + v01.x, 0.f);
                float s1 = fmaxf(u01.y + v01.y, 0.f);
                float s2 = fmaxf(u23.x + v23.x, 0.f);
                float s3 = fmaxf(u23.y + v23.y, 0.f);
                p2.x = fmaf(s0, w2r[4 * w + 0], p2.x);
                p2.y = fmaf(s1, w2r[4 * w + 1], p2.y);
                p2.x = fmaf(s2, w2r[4 * w + 2], p2.x);
                p2.y = fmaf(s3, w2r[4 * w + 3], p2.y);
            }
            p = p2.x + p2.y;
#pragma unroll
            for (int off = 1; off < 16; off <<= 1)
                p += __shfl_xor(p, off, 64);
            if (c == 0) out[e1] = 1.f / (1.f + __expf(-(p + b2)));
        }
    }
}

extern "C" void kernel_launch(void* const* d_in, const int* in_sizes, int n_in,
                              void* d_out, int out_size, void* d_ws, size_t ws_size,
                              hipStream_t stream) {
    const float* x  = (const float*)d_in[0];
    const int*   ei = (const int*)d_in[1];
    const float* W1 = (const float*)d_in[2];
    const float* b1 = (const float*)d_in[3];
    const float* W2 = (const float*)d_in[4];
    const float* b2 = (const float*)d_in[5];
    float* out = (float*)d_out;

    const int N = in_sizes[0] / 256;   // 10000
    const int E = in_sizes[1] / 2;     // 320000

    unsigned char*  uv = (unsigned char*)d_ws;            // N*512 fp8 (5.12 MB)
    unsigned short* wb = (unsigned short*)(uv + (size_t)N * 512); // 256KB bf16

    const int nw4 = (256 * 512) / 4;
    convert_w<<<(nw4 + 255) / 256, 256, 0, stream>>>(W1, wb, nw4);

    dim3 g((N + 15) / 16, 2);          // (625, 2) = 1250 blocks
    gemm_mfma<<<g, 256, 0, stream>>>(x, wb, b1, uv, N);

    edge_kernel<<<2048, 256, 0, stream>>>(uv, ei, W2, b2, out, E);
}